// Round 2
// baseline (384.632 us; speedup 1.0000x reference)
//
#include <hip/hip_runtime.h>

typedef __attribute__((ext_vector_type(4))) float  f32x4;
typedef __attribute__((ext_vector_type(4))) float  float4v;
typedef __attribute__((ext_vector_type(8))) short  short8;
typedef __attribute__((ext_vector_type(4))) short  short4v;

#define TQ 1500
#define TP 1536
#define CC 1024
#define EPS 1e-6f

// ---------------- workspace layout (bytes) ----------------
#define XT_OFF    ((size_t)0)          // (B,TP,CC) bf16 = 25165824  (reused as outT)
#define XAT_OFF   ((size_t)25165824)   // (B,TP,CC) bf16
#define PQT_OFF   ((size_t)50331648)   // (B,TP,CC) bf16
#define WB_OFF    ((size_t)75497472)   // 4x (CC,CC) bf16 = 8388608
#define KSUM_OFF  ((size_t)83886080)   // (B,CC) f32 = 32768
#define KVSUM_OFF ((size_t)83918848)   // (B,CC) f32 = 32768
#define IDEN_OFF  ((size_t)83951616)   // (B,16,TP) f32 = 786432

__device__ __forceinline__ float bf2f(short s) {
    union { unsigned u; float f; } v; v.u = ((unsigned)(unsigned short)s) << 16; return v.f;
}
__device__ __forceinline__ short f2bf(float f) {
    union { float f; unsigned u; } v; v.f = f;
    unsigned r = (v.u + 0x7FFFu + ((v.u >> 16) & 1u)) >> 16;
    return (short)r;
}
__device__ __forceinline__ float phi_f(float x) {
    return x / (1.f + __expf(-x)) + 1.f;   // silu(x)+1
}
__device__ __forceinline__ void gl_lds16(const void* g, void* l) {
    __builtin_amdgcn_global_load_lds((const __attribute__((address_space(1))) void*)g,
                                     (__attribute__((address_space(3))) void*)l, 16, 0, 0);
}

// ---------------- weight cast fp32 -> bf16 ----------------
__global__ __launch_bounds__(256)
void conv_w_kernel(const float* __restrict__ w0, const float* __restrict__ w1,
                   const float* __restrict__ w2, const float* __restrict__ w3,
                   short* __restrict__ o0, short* __restrict__ o1,
                   short* __restrict__ o2, short* __restrict__ o3)
{
    const int i = (blockIdx.x * 256 + threadIdx.x) * 4;
    float4v a = *(const float4v*)(w0 + i);
    float4v b = *(const float4v*)(w1 + i);
    float4v c = *(const float4v*)(w2 + i);
    float4v d = *(const float4v*)(w3 + i);
    short4v ra, rb, rc, rd;
#pragma unroll
    for (int j = 0; j < 4; ++j) {
        ra[j] = f2bf(a[j]); rb[j] = f2bf(b[j]); rc[j] = f2bf(c[j]); rd[j] = f2bf(d[j]);
    }
    *(short4v*)(o0 + i) = ra;
    *(short4v*)(o1 + i) = rb;
    *(short4v*)(o2 + i) = rc;
    *(short4v*)(o3 + i) = rd;
}

// ------------- transpose-cast (B,C,T)fp32 -> (B,TP,C)bf16, zero-pad t>=TQ -------------
__global__ __launch_bounds__(256)
void xpose_kernel(const float* __restrict__ x, short* __restrict__ xT)
{
    __shared__ float tile[64][65];
    const int b  = blockIdx.z;
    const int c0 = blockIdx.y * 64;
    const int t0 = blockIdx.x * 64;
    const int tl = threadIdx.x & 63;
    const int q  = threadIdx.x >> 6;
    const int t  = t0 + tl;
#pragma unroll
    for (int i = 0; i < 16; ++i) {
        const int cl = q * 16 + i;
        float v = 0.f;
        if (t < TQ) v = x[((size_t)b * CC + c0 + cl) * TQ + t];
        tile[cl][tl] = v;
    }
    __syncthreads();
#pragma unroll
    for (int i = 0; i < 16; ++i) {
        const int t2 = q * 16 + i;
        xT[((size_t)b * TP + t0 + t2) * CC + c0 + tl] = f2bf(tile[tl][t2]);
    }
}

// ---------------- gemm_q : pqT[b][t][c] = phi(Wq x + bq), m=t n=c ----------------
__global__ __launch_bounds__(256)
void gemm_q_kernel(const short* __restrict__ xT, const short* __restrict__ Wqb,
                   const float* __restrict__ bq, short* __restrict__ pqT)
{
    __shared__ short As[128 * 32];
    __shared__ short Bs[128 * 32];
    const int b    = blockIdx.z;
    const int mt   = blockIdx.y;   // t-tile (12)
    const int nt   = blockIdx.x;   // c-tile (8)
    const int tid  = threadIdx.x;
    const int wave = tid >> 6, lane = tid & 63;
    const int wr = wave >> 1, wc = wave & 1;
    const int srow = lane >> 2;
    const int skof = (lane & 3) << 3;
    const int rl   = lane & 15;
    const int rg   = (lane >> 4) << 3;
    const int rgrp = lane >> 4;

    const short* Ab = xT + (size_t)b * TP * CC + (size_t)mt * 128 * CC;
    const short* Bb = Wqb + (size_t)nt * 128 * CC;

    f32x4 acc[4][4] = {};

    for (int kt = 0; kt < CC / 32; ++kt) {
        const int k0 = kt << 5;
#pragma unroll
        for (int c2 = 0; c2 < 2; ++c2) {
            const int ch = wave * 2 + c2;
            gl_lds16(Ab + (size_t)(ch * 16 + srow) * CC + k0 + skof, &As[ch * 512]);
            gl_lds16(Bb + (size_t)(ch * 16 + srow) * CC + k0 + skof, &Bs[ch * 512]);
        }
        __syncthreads();
        short8 ra[4], rb[4];
#pragma unroll
        for (int i = 0; i < 4; ++i) {
            ra[i] = *(const short8*)&As[(wr * 64 + i * 16 + rl) * 32 + rg];
            rb[i] = *(const short8*)&Bs[(wc * 64 + i * 16 + rl) * 32 + rg];
        }
#pragma unroll
        for (int i = 0; i < 4; ++i)
#pragma unroll
            for (int j = 0; j < 4; ++j)
                acc[i][j] = __builtin_amdgcn_mfma_f32_16x16x32_bf16(ra[i], rb[j], acc[i][j], 0, 0, 0);
        __syncthreads();
    }

#pragma unroll
    for (int j = 0; j < 4; ++j) {
        const int c = nt * 128 + wc * 64 + j * 16 + rl;
        const float bias = bq[c];
#pragma unroll
        for (int i = 0; i < 4; ++i) {
            const int tbase = mt * 128 + wr * 64 + i * 16 + rgrp * 4;
#pragma unroll
            for (int r = 0; r < 4; ++r) {
                float v = acc[i][j][r] + bias;
                pqT[((size_t)b * TP + tbase + r) * CC + c] = f2bf(phi_f(v));
            }
        }
    }
}

// ------- gemm_kv : dual GEMM (k,v) with fused phi + reduction over t -> ksum/kvsum -------
__global__ __launch_bounds__(256)
void gemm_kv_kernel(const short* __restrict__ xaT, const short* __restrict__ Wkb,
                    const short* __restrict__ Wvb, const float* __restrict__ bv,
                    float* __restrict__ ksum, float* __restrict__ kvsum)
{
    __shared__ short As[128 * 32];
    __shared__ short Bks[64 * 32];
    __shared__ short Bvs[64 * 32];
    const int b    = blockIdx.z;
    const int mt   = blockIdx.y;   // t-tile (12)
    const int nt   = blockIdx.x;   // c-tile (16), BN=64
    const int tid  = threadIdx.x;
    const int wave = tid >> 6, lane = tid & 63;
    const int wr = wave >> 1, wc = wave & 1;
    const int srow = lane >> 2;
    const int skof = (lane & 3) << 3;
    const int rl   = lane & 15;
    const int rg   = (lane >> 4) << 3;
    const int rgrp = lane >> 4;

    const short* Ab  = xaT + (size_t)b * TP * CC + (size_t)mt * 128 * CC;
    const short* Bkb = Wkb + (size_t)nt * 64 * CC;
    const short* Bvb = Wvb + (size_t)nt * 64 * CC;

    f32x4 ak[4][2] = {};
    f32x4 av[4][2] = {};

    for (int kt = 0; kt < CC / 32; ++kt) {
        const int k0 = kt << 5;
#pragma unroll
        for (int c2 = 0; c2 < 2; ++c2) {
            const int ch = wave * 2 + c2;
            gl_lds16(Ab + (size_t)(ch * 16 + srow) * CC + k0 + skof, &As[ch * 512]);
        }
        gl_lds16(Bkb + (size_t)(wave * 16 + srow) * CC + k0 + skof, &Bks[wave * 512]);
        gl_lds16(Bvb + (size_t)(wave * 16 + srow) * CC + k0 + skof, &Bvs[wave * 512]);
        __syncthreads();
        short8 ra[4], rk[2], rv[2];
#pragma unroll
        for (int i = 0; i < 4; ++i)
            ra[i] = *(const short8*)&As[(wr * 64 + i * 16 + rl) * 32 + rg];
#pragma unroll
        for (int j = 0; j < 2; ++j) {
            rk[j] = *(const short8*)&Bks[(wc * 32 + j * 16 + rl) * 32 + rg];
            rv[j] = *(const short8*)&Bvs[(wc * 32 + j * 16 + rl) * 32 + rg];
        }
#pragma unroll
        for (int i = 0; i < 4; ++i)
#pragma unroll
            for (int j = 0; j < 2; ++j) {
                ak[i][j] = __builtin_amdgcn_mfma_f32_16x16x32_bf16(ra[i], rk[j], ak[i][j], 0, 0, 0);
                av[i][j] = __builtin_amdgcn_mfma_f32_16x16x32_bf16(ra[i], rv[j], av[i][j], 0, 0, 0);
            }
        __syncthreads();
    }

#pragma unroll
    for (int j = 0; j < 2; ++j) {
        const int c = nt * 64 + wc * 32 + j * 16 + rl;
        const float bvc = bv[c];
        float sk = 0.f, skv = 0.f;
#pragma unroll
        for (int i = 0; i < 4; ++i) {
            const int tbase = mt * 128 + wr * 64 + i * 16 + rgrp * 4;
#pragma unroll
            for (int r = 0; r < 4; ++r) {
                if (tbase + r < TQ) {
                    float pk = phi_f(ak[i][j][r]);
                    float vv = av[i][j][r] + bvc;
                    sk  += pk;
                    skv += pk * vv;
                }
            }
        }
        sk  += __shfl_xor(sk, 16);  sk  += __shfl_xor(sk, 32);
        skv += __shfl_xor(skv, 16); skv += __shfl_xor(skv, 32);
        if (rgrp == 0) {
            atomicAdd(&ksum[b * CC + c], sk);
            atomicAdd(&kvsum[b * CC + c], skv);
        }
    }
}

// ---------------- den: invden[b][h][t] = 0.125/(sum_d pq*ksum + eps) ----------------
__global__ __launch_bounds__(64)
void den_kernel(const short* __restrict__ pqT, const float* __restrict__ ksum,
                float* __restrict__ invden)
{
    const int b = blockIdx.z, h = blockIdx.y;
    const int t = blockIdx.x * 64 + threadIdx.x;
    const short* row = pqT + ((size_t)b * TP + t) * CC + h * 64;
    const float* ks  = ksum + b * CC + h * 64;
    float s = 0.f;
#pragma unroll
    for (int i = 0; i < 8; ++i) {
        short8 p = *(const short8*)&row[i * 8];
#pragma unroll
        for (int j = 0; j < 8; ++j)
            s += bf2f(p[j]) * ks[i * 8 + j];
    }
    invden[((size_t)b * 16 + h) * TP + t] = 0.125f / (s + EPS);
}

// ---------------- out: outT = pq * kvsum[c] * invden[h][t] ----------------
__global__ __launch_bounds__(128)
void out_kernel(const short* __restrict__ pqT, const float* __restrict__ kvsum,
                const float* __restrict__ invden, short* __restrict__ outT)
{
    const int t = blockIdx.x, b = blockIdx.y;
    const int c0 = threadIdx.x * 8;
    const size_t base = ((size_t)b * TP + t) * CC + c0;
    short8 p = *(const short8*)(pqT + base);
    const float id = invden[((size_t)b * 16 + (c0 >> 6)) * TP + t];
    const float* kv = kvsum + b * CC + c0;
    short8 o;
#pragma unroll
    for (int j = 0; j < 8; ++j)
        o[j] = f2bf(bf2f(p[j]) * kv[j] * id);
    *(short8*)(outT + base) = o;
}

// ---------------- gemm_o : y[b][c][t] = Wo out + bo, m=c n=t, mask t<TQ ----------------
__global__ __launch_bounds__(256)
void gemm_o_kernel(const short* __restrict__ Wob, const short* __restrict__ outT,
                   const float* __restrict__ bo, float* __restrict__ y)
{
    __shared__ short As[128 * 32];
    __shared__ short Bs[128 * 32];
    const int b    = blockIdx.z;
    const int ct   = blockIdx.y;   // c-tile (8)
    const int tt   = blockIdx.x;   // t-tile (12)
    const int tid  = threadIdx.x;
    const int wave = tid >> 6, lane = tid & 63;
    const int wr = wave >> 1, wc = wave & 1;
    const int srow = lane >> 2;
    const int skof = (lane & 3) << 3;
    const int rl   = lane & 15;
    const int rg   = (lane >> 4) << 3;
    const int rgrp = lane >> 4;

    const short* Ab = Wob + (size_t)ct * 128 * CC;
    const short* Bb = outT + (size_t)b * TP * CC + (size_t)tt * 128 * CC;

    f32x4 acc[4][4] = {};

    for (int kt = 0; kt < CC / 32; ++kt) {
        const int k0 = kt << 5;
#pragma unroll
        for (int c2 = 0; c2 < 2; ++c2) {
            const int ch = wave * 2 + c2;
            gl_lds16(Ab + (size_t)(ch * 16 + srow) * CC + k0 + skof, &As[ch * 512]);
            gl_lds16(Bb + (size_t)(ch * 16 + srow) * CC + k0 + skof, &Bs[ch * 512]);
        }
        __syncthreads();
        short8 ra[4], rb[4];
#pragma unroll
        for (int i = 0; i < 4; ++i) {
            ra[i] = *(const short8*)&As[(wr * 64 + i * 16 + rl) * 32 + rg];
            rb[i] = *(const short8*)&Bs[(wc * 64 + i * 16 + rl) * 32 + rg];
        }
#pragma unroll
        for (int i = 0; i < 4; ++i)
#pragma unroll
            for (int j = 0; j < 4; ++j)
                acc[i][j] = __builtin_amdgcn_mfma_f32_16x16x32_bf16(ra[i], rb[j], acc[i][j], 0, 0, 0);
        __syncthreads();
    }

#pragma unroll
    for (int j = 0; j < 4; ++j) {
        const int tcol = tt * 128 + wc * 64 + j * 16 + rl;
        if (tcol >= TQ) continue;
#pragma unroll
        for (int i = 0; i < 4; ++i) {
            const int cbase = ct * 128 + wr * 64 + i * 16 + rgrp * 4;
#pragma unroll
            for (int r = 0; r < 4; ++r) {
                const int c = cbase + r;
                y[((size_t)b * CC + c) * TQ + tcol] = acc[i][j][r] + bo[c];
            }
        }
    }
}

extern "C" void kernel_launch(void* const* d_in, const int* in_sizes, int n_in,
                              void* d_out, int out_size, void* d_ws, size_t ws_size,
                              hipStream_t stream)
{
    (void)in_sizes; (void)n_in; (void)out_size; (void)ws_size;
    const float* x  = (const float*)d_in[0];
    const float* xa = (const float*)d_in[1];
    const float* Wq = (const float*)d_in[2];
    const float* bq = (const float*)d_in[3];
    const float* Wk = (const float*)d_in[4];
    const float* Wv = (const float*)d_in[5];
    const float* bv = (const float*)d_in[6];
    const float* Wo = (const float*)d_in[7];
    const float* bo = (const float*)d_in[8];
    float* y = (float*)d_out;
    char* ws = (char*)d_ws;

    short* xT    = (short*)(ws + XT_OFF);
    short* xaT   = (short*)(ws + XAT_OFF);
    short* pqT   = (short*)(ws + PQT_OFF);
    short* Wqb   = (short*)(ws + WB_OFF);
    short* Wkb   = Wqb + (size_t)CC * CC;
    short* Wvb   = Wkb + (size_t)CC * CC;
    short* Wob   = Wvb + (size_t)CC * CC;
    float* ksum  = (float*)(ws + KSUM_OFF);
    float* kvsum = (float*)(ws + KVSUM_OFF);
    float* iden  = (float*)(ws + IDEN_OFF);
    short* outT  = xT;  // reuse: xT no longer needed once gemm_q is done

    conv_w_kernel<<<dim3(CC * CC / 4 / 256), 256, 0, stream>>>(Wq, Wk, Wv, Wo, Wqb, Wkb, Wvb, Wob);
    xpose_kernel<<<dim3(TP / 64, CC / 64, 8), 256, 0, stream>>>(x, xT);
    xpose_kernel<<<dim3(TP / 64, CC / 64, 8), 256, 0, stream>>>(xa, xaT);
    hipMemsetAsync(ws + KSUM_OFF, 0, 65536, stream);

    gemm_kv_kernel<<<dim3(CC / 64, TP / 128, 8), 256, 0, stream>>>(xaT, Wkb, Wvb, bv, ksum, kvsum);
    gemm_q_kernel<<<dim3(CC / 128, TP / 128, 8), 256, 0, stream>>>(xT, Wqb, bq, pqT);
    den_kernel<<<dim3(TP / 64, 16, 8), 64, 0, stream>>>(pqT, ksum, iden);
    out_kernel<<<dim3(TP, 8), 128, 0, stream>>>(pqT, kvsum, iden, outT);
    gemm_o_kernel<<<dim3(TP / 128, CC / 128, 8), 256, 0, stream>>>(Wob, outT, bo, y);
}

// Round 5
// 358.659 us; speedup vs baseline: 1.0724x; 1.0724x over previous
//
#include <hip/hip_runtime.h>

typedef __attribute__((ext_vector_type(4))) float  f32x4;
typedef __attribute__((ext_vector_type(4))) float  float4v;
typedef __attribute__((ext_vector_type(8))) short  short8;
typedef __attribute__((ext_vector_type(4))) short  short4v;

#define TQ 1500
#define TP 1536
#define CC 1024
#define EPS 1e-6f

// ---------------- workspace layout (bytes) ----------------
#define XT_OFF    ((size_t)0)          // (B,TP,CC) bf16 = 25165824
#define XAT_OFF   ((size_t)25165824)   // (B,TP,CC) bf16
#define OUT_OFF   ((size_t)50331648)   // (B,TP,CC) bf16 (outT)
#define WB_OFF    ((size_t)75497472)   // 4x (CC,CC) bf16 = 8388608
#define KSUM_OFF  ((size_t)83886080)   // (B,CC) f32 = 32768
#define KVSUM_OFF ((size_t)83918848)   // (B,CC) f32 = 32768

__device__ __forceinline__ float bf2f(short s) {
    union { unsigned u; float f; } v; v.u = ((unsigned)(unsigned short)s) << 16; return v.f;
}
__device__ __forceinline__ short f2bf(float f) {
    union { float f; unsigned u; } v; v.f = f;
    unsigned r = (v.u + 0x7FFFu + ((v.u >> 16) & 1u)) >> 16;
    return (short)r;
}
__device__ __forceinline__ float phi_f(float x) {
    return x / (1.f + __expf(-x)) + 1.f;   // silu(x)+1
}
__device__ __forceinline__ void gl_lds16(const void* g, void* l) {
    __builtin_amdgcn_global_load_lds((const __attribute__((address_space(1))) void*)g,
                                     (__attribute__((address_space(3))) void*)l, 16, 0, 0);
}

// LDS slot swizzle: rows advance in multiples of 16 everywhere, so
// (row>>1)&3 == (srow>>1)&3 (stage) == (rl>>1)&3 (read) — per-lane constants.
// Stage side pre-swizzles the GLOBAL source (LDS dest stays linear for
// global_load_lds); read side applies the same XOR. 8-way -> 2-way (free).

// ---------------- weight cast fp32 -> bf16 ----------------
__global__ __launch_bounds__(256)
void conv_w_kernel(const float* __restrict__ w0, const float* __restrict__ w1,
                   const float* __restrict__ w2, const float* __restrict__ w3,
                   short* __restrict__ o0, short* __restrict__ o1,
                   short* __restrict__ o2, short* __restrict__ o3)
{
    const int i = (blockIdx.x * 256 + threadIdx.x) * 4;
    float4v a = *(const float4v*)(w0 + i);
    float4v b = *(const float4v*)(w1 + i);
    float4v c = *(const float4v*)(w2 + i);
    float4v d = *(const float4v*)(w3 + i);
    short4v ra, rb, rc, rd;
#pragma unroll
    for (int j = 0; j < 4; ++j) {
        ra[j] = f2bf(a[j]); rb[j] = f2bf(b[j]); rc[j] = f2bf(c[j]); rd[j] = f2bf(d[j]);
    }
    *(short4v*)(o0 + i) = ra;
    *(short4v*)(o1 + i) = rb;
    *(short4v*)(o2 + i) = rc;
    *(short4v*)(o3 + i) = rd;
}

// ------- transpose-cast (B,C,T)fp32 -> (B,TP,C)bf16, zero-pad t>=TQ; x and xa merged -------
__global__ __launch_bounds__(256)
void xpose_kernel(const float* __restrict__ x, const float* __restrict__ xa,
                  short* __restrict__ xT, short* __restrict__ xaT)
{
    __shared__ float tile[64][65];
    const int z  = blockIdx.z;
    const int b  = z & 7;
    const float* src = (z < 8) ? x : xa;
    short* dst       = (z < 8) ? xT : xaT;
    const int c0 = blockIdx.y * 64;
    const int t0 = blockIdx.x * 64;
    const int tl = threadIdx.x & 63;
    const int q  = threadIdx.x >> 6;
    const int t  = t0 + tl;
#pragma unroll
    for (int i = 0; i < 16; ++i) {
        const int cl = q * 16 + i;
        float v = 0.f;
        if (t < TQ) v = src[((size_t)b * CC + c0 + cl) * TQ + t];
        tile[cl][tl] = v;
    }
    __syncthreads();
#pragma unroll
    for (int i = 0; i < 16; ++i) {
        const int t2 = q * 16 + i;
        dst[((size_t)b * TP + t0 + t2) * CC + c0 + tl] = f2bf(tile[tl][t2]);
    }
}

// ------- gemm_kv : dual GEMM (k,v) with fused phi + reduction over t -> ksum/kvsum -------
// flat grid 1536, XCD-swizzled, nt fastest within XCD
__global__ __launch_bounds__(256)
void gemm_kv_kernel(const short* __restrict__ xaT, const short* __restrict__ Wkb,
                    const short* __restrict__ Wvb, const float* __restrict__ bv,
                    float* __restrict__ ksum, float* __restrict__ kvsum)
{
    __shared__ short As[128 * 32];
    __shared__ short Bks[64 * 32];
    __shared__ short Bvs[64 * 32];
    const int f  = blockIdx.x;
    const int L  = (f & 7) * 192 + (f >> 3);
    const int nt = L % 16;
    const int mt = (L / 16) % 12;
    const int b  = L / 192;
    const int tid  = threadIdx.x;
    const int wave = tid >> 6, lane = tid & 63;
    const int wr = wave >> 1, wc = wave & 1;
    const int srow = lane >> 2;
    const int skof = (((lane & 3) ^ ((srow >> 1) & 3)) << 3);   // swizzled stage slot
    const int rl   = lane & 15;
    const int rg   = ((((lane >> 4)) ^ ((rl >> 1) & 3)) << 3);  // swizzled read slot
    const int rgrp = lane >> 4;

    const short* Ab  = xaT + (size_t)b * TP * CC + (size_t)mt * 128 * CC;
    const short* Bkb = Wkb + (size_t)nt * 64 * CC;
    const short* Bvb = Wvb + (size_t)nt * 64 * CC;

    f32x4 ak[4][2] = {};
    f32x4 av[4][2] = {};

    for (int kt = 0; kt < CC / 32; ++kt) {
        const int k0 = kt << 5;
#pragma unroll
        for (int c2 = 0; c2 < 2; ++c2) {
            const int ch = wave * 2 + c2;
            gl_lds16(Ab + (size_t)(ch * 16 + srow) * CC + k0 + skof, &As[ch * 512]);
        }
        gl_lds16(Bkb + (size_t)(wave * 16 + srow) * CC + k0 + skof, &Bks[wave * 512]);
        gl_lds16(Bvb + (size_t)(wave * 16 + srow) * CC + k0 + skof, &Bvs[wave * 512]);
        __syncthreads();
        short8 ra[4], rk[2], rv[2];
#pragma unroll
        for (int i = 0; i < 4; ++i)
            ra[i] = *(const short8*)&As[(wr * 64 + i * 16 + rl) * 32 + rg];
#pragma unroll
        for (int j = 0; j < 2; ++j) {
            rk[j] = *(const short8*)&Bks[(wc * 32 + j * 16 + rl) * 32 + rg];
            rv[j] = *(const short8*)&Bvs[(wc * 32 + j * 16 + rl) * 32 + rg];
        }
#pragma unroll
        for (int i = 0; i < 4; ++i)
#pragma unroll
            for (int j = 0; j < 2; ++j) {
                ak[i][j] = __builtin_amdgcn_mfma_f32_16x16x32_bf16(ra[i], rk[j], ak[i][j], 0, 0, 0);
                av[i][j] = __builtin_amdgcn_mfma_f32_16x16x32_bf16(ra[i], rv[j], av[i][j], 0, 0, 0);
            }
        __syncthreads();
    }

#pragma unroll
    for (int j = 0; j < 2; ++j) {
        const int c = nt * 64 + wc * 32 + j * 16 + rl;
        const float bvc = bv[c];
        float sk = 0.f, skv = 0.f;
#pragma unroll
        for (int i = 0; i < 4; ++i) {
            const int tbase = mt * 128 + wr * 64 + i * 16 + rgrp * 4;
#pragma unroll
            for (int r = 0; r < 4; ++r) {
                if (tbase + r < TQ) {
                    float pk = phi_f(ak[i][j][r]);
                    float vv = av[i][j][r] + bvc;
                    sk  += pk;
                    skv += pk * vv;
                }
            }
        }
        sk  += __shfl_xor(sk, 16);  sk  += __shfl_xor(sk, 32);
        skv += __shfl_xor(skv, 16); skv += __shfl_xor(skv, 32);
        if (rgrp == 0) {
            atomicAdd(&ksum[b * CC + c], sk);
            atomicAdd(&kvsum[b * CC + c], skv);
        }
    }
}

// ------- gemm_q_out : pq = phi(Wq x + bq); den-reduce in epilogue; outT = pq*kvsum*0.125/(den+eps) -------
// A 128x128 c-tile spans exactly 2 heads; wc's 64-col half is ONE full head.
// flat grid 768, XCD-swizzled, nt fastest
__global__ __launch_bounds__(256)
void gemm_q_out_kernel(const short* __restrict__ xT, const short* __restrict__ Wqb,
                       const float* __restrict__ bq, const float* __restrict__ ksum,
                       const float* __restrict__ kvsum, short* __restrict__ outT)
{
    __shared__ short As[128 * 32];
    __shared__ short Bs[128 * 32];
    const int f  = blockIdx.x;
    const int L  = (f & 7) * 96 + (f >> 3);
    const int nt = L % 8;
    const int mt = (L / 8) % 12;
    const int b  = L / 96;
    const int tid  = threadIdx.x;
    const int wave = tid >> 6, lane = tid & 63;
    const int wr = wave >> 1, wc = wave & 1;
    const int srow = lane >> 2;
    const int skof = (((lane & 3) ^ ((srow >> 1) & 3)) << 3);
    const int rl   = lane & 15;
    const int rg   = ((((lane >> 4)) ^ ((rl >> 1) & 3)) << 3);
    const int rgrp = lane >> 4;

    const short* Ab = xT + (size_t)b * TP * CC + (size_t)mt * 128 * CC;
    const short* Bb = Wqb + (size_t)nt * 128 * CC;

    f32x4 acc[4][4] = {};

    for (int kt = 0; kt < CC / 32; ++kt) {
        const int k0 = kt << 5;
#pragma unroll
        for (int c2 = 0; c2 < 2; ++c2) {
            const int ch = wave * 2 + c2;
            gl_lds16(Ab + (size_t)(ch * 16 + srow) * CC + k0 + skof, &As[ch * 512]);
            gl_lds16(Bb + (size_t)(ch * 16 + srow) * CC + k0 + skof, &Bs[ch * 512]);
        }
        __syncthreads();
        short8 ra[4], rb[4];
#pragma unroll
        for (int i = 0; i < 4; ++i) {
            ra[i] = *(const short8*)&As[(wr * 64 + i * 16 + rl) * 32 + rg];
            rb[i] = *(const short8*)&Bs[(wc * 64 + i * 16 + rl) * 32 + rg];
        }
#pragma unroll
        for (int i = 0; i < 4; ++i)
#pragma unroll
            for (int j = 0; j < 4; ++j)
                acc[i][j] = __builtin_amdgcn_mfma_f32_16x16x32_bf16(ra[i], rb[j], acc[i][j], 0, 0, 0);
        __syncthreads();
    }

    // ---- fused epilogue ----
    float bias[4], ks[4], kv[4];
#pragma unroll
    for (int j = 0; j < 4; ++j) {
        const int c = nt * 128 + wc * 64 + j * 16 + rl;
        bias[j] = bq[c];
        ks[j]   = ksum[b * CC + c];
        kv[j]   = kvsum[b * CC + c];
    }
    // acc -> pq in place
#pragma unroll
    for (int i = 0; i < 4; ++i)
#pragma unroll
        for (int j = 0; j < 4; ++j)
#pragma unroll
            for (int r = 0; r < 4; ++r)
                acc[i][j][r] = phi_f(acc[i][j][r] + bias[j]);
    // den over the head's 64 channels: per-thread partial over j, then reduce over rl lanes
#pragma unroll
    for (int i = 0; i < 4; ++i) {
#pragma unroll
        for (int r = 0; r < 4; ++r) {
            float d = acc[i][0][r] * ks[0] + acc[i][1][r] * ks[1]
                    + acc[i][2][r] * ks[2] + acc[i][3][r] * ks[3];
            d += __shfl_xor(d, 1); d += __shfl_xor(d, 2);
            d += __shfl_xor(d, 4); d += __shfl_xor(d, 8);
            const float inv = 0.125f / (d + EPS);
            const int t = mt * 128 + wr * 64 + i * 16 + rgrp * 4 + r;
#pragma unroll
            for (int j = 0; j < 4; ++j) {
                const int c = nt * 128 + wc * 64 + j * 16 + rl;
                outT[((size_t)b * TP + t) * CC + c] = f2bf(acc[i][j][r] * kv[j] * inv);
            }
        }
    }
}

// ---------------- gemm_o : y[b][c][t] = Wo out + bo, m=c n=t, mask t<TQ ----------------
// flat grid 768, XCD-swizzled, tt fastest
__global__ __launch_bounds__(256)
void gemm_o_kernel(const short* __restrict__ Wob, const short* __restrict__ outT,
                   const float* __restrict__ bo, float* __restrict__ y)
{
    __shared__ short As[128 * 32];
    __shared__ short Bs[128 * 32];
    const int f  = blockIdx.x;
    const int L  = (f & 7) * 96 + (f >> 3);
    const int tt = L % 12;
    const int ct = (L / 12) % 8;
    const int b  = L / 96;
    const int tid  = threadIdx.x;
    const int wave = tid >> 6, lane = tid & 63;
    const int wr = wave >> 1, wc = wave & 1;
    const int srow = lane >> 2;
    const int skof = (((lane & 3) ^ ((srow >> 1) & 3)) << 3);
    const int rl   = lane & 15;
    const int rg   = ((((lane >> 4)) ^ ((rl >> 1) & 3)) << 3);
    const int rgrp = lane >> 4;

    const short* Ab = Wob + (size_t)ct * 128 * CC;
    const short* Bb = outT + (size_t)b * TP * CC + (size_t)tt * 128 * CC;

    f32x4 acc[4][4] = {};

    for (int kt = 0; kt < CC / 32; ++kt) {
        const int k0 = kt << 5;
#pragma unroll
        for (int c2 = 0; c2 < 2; ++c2) {
            const int ch = wave * 2 + c2;
            gl_lds16(Ab + (size_t)(ch * 16 + srow) * CC + k0 + skof, &As[ch * 512]);
            gl_lds16(Bb + (size_t)(ch * 16 + srow) * CC + k0 + skof, &Bs[ch * 512]);
        }
        __syncthreads();
        short8 ra[4], rb[4];
#pragma unroll
        for (int i = 0; i < 4; ++i) {
            ra[i] = *(const short8*)&As[(wr * 64 + i * 16 + rl) * 32 + rg];
            rb[i] = *(const short8*)&Bs[(wc * 64 + i * 16 + rl) * 32 + rg];
        }
#pragma unroll
        for (int i = 0; i < 4; ++i)
#pragma unroll
            for (int j = 0; j < 4; ++j)
                acc[i][j] = __builtin_amdgcn_mfma_f32_16x16x32_bf16(ra[i], rb[j], acc[i][j], 0, 0, 0);
        __syncthreads();
    }

#pragma unroll
    for (int j = 0; j < 4; ++j) {
        const int tcol = tt * 128 + wc * 64 + j * 16 + rl;
        if (tcol >= TQ) continue;
#pragma unroll
        for (int i = 0; i < 4; ++i) {
            const int cbase = ct * 128 + wr * 64 + i * 16 + rgrp * 4;
#pragma unroll
            for (int r = 0; r < 4; ++r) {
                const int c = cbase + r;
                y[((size_t)b * CC + c) * TQ + tcol] = acc[i][j][r] + bo[c];
            }
        }
    }
}

extern "C" void kernel_launch(void* const* d_in, const int* in_sizes, int n_in,
                              void* d_out, int out_size, void* d_ws, size_t ws_size,
                              hipStream_t stream)
{
    (void)in_sizes; (void)n_in; (void)out_size; (void)ws_size;
    const float* x  = (const float*)d_in[0];
    const float* xa = (const float*)d_in[1];
    const float* Wq = (const float*)d_in[2];
    const float* bq = (const float*)d_in[3];
    const float* Wk = (const float*)d_in[4];
    const float* Wv = (const float*)d_in[5];
    const float* bv = (const float*)d_in[6];
    const float* Wo = (const float*)d_in[7];
    const float* bo = (const float*)d_in[8];
    float* y = (float*)d_out;
    char* ws = (char*)d_ws;

    short* xT    = (short*)(ws + XT_OFF);
    short* xaT   = (short*)(ws + XAT_OFF);
    short* outT  = (short*)(ws + OUT_OFF);
    short* Wqb   = (short*)(ws + WB_OFF);
    short* Wkb   = Wqb + (size_t)CC * CC;
    short* Wvb   = Wkb + (size_t)CC * CC;
    short* Wob   = Wvb + (size_t)CC * CC;
    float* ksum  = (float*)(ws + KSUM_OFF);
    float* kvsum = (float*)(ws + KVSUM_OFF);

    conv_w_kernel<<<dim3(CC * CC / 4 / 256), 256, 0, stream>>>(Wq, Wk, Wv, Wo, Wqb, Wkb, Wvb, Wob);
    xpose_kernel<<<dim3(TP / 64, CC / 64, 16), 256, 0, stream>>>(x, xa, xT, xaT);
    hipMemsetAsync(ws + KSUM_OFF, 0, 65536, stream);

    gemm_kv_kernel<<<dim3(1536), 256, 0, stream>>>(xaT, Wkb, Wvb, bv, ksum, kvsum);
    gemm_q_out_kernel<<<dim3(768), 256, 0, stream>>>(xT, Wqb, bq, ksum, kvsum, outT);
    gemm_o_kernel<<<dim3(768), 256, 0, stream>>>(Wob, outT, bo, y);
}

// Round 8
// 321.281 us; speedup vs baseline: 1.1972x; 1.1163x over previous
//
#include <hip/hip_runtime.h>

typedef __attribute__((ext_vector_type(4))) float  f32x4;
typedef __attribute__((ext_vector_type(4))) float  float4v;
typedef __attribute__((ext_vector_type(8))) short  short8;
typedef __attribute__((ext_vector_type(4))) short  short4v;

#define TQ 1500
#define TP 1536
#define CC 1024
#define EPS 1e-6f

// ---------------- workspace layout (bytes) ----------------
#define XT_OFF    ((size_t)0)          // (B,TP,CC) bf16 = 25165824  (flat 12288 x 1024)
#define XAT_OFF   ((size_t)25165824)   // (B,TP,CC) bf16
#define OUT_OFF   ((size_t)50331648)   // (B,TP,CC) bf16 (outT, flat 12288 x 1024)
#define WB_OFF    ((size_t)75497472)   // 4x (CC,CC) bf16 = 8388608
#define KSUM_OFF  ((size_t)83886080)   // (B,CC) f32 = 32768
#define KVSUM_OFF ((size_t)83918848)   // (B,CC) f32 = 32768

#define VMCNT4() asm volatile("s_waitcnt vmcnt(4)" ::: "memory")
#define VMCNT2() asm volatile("s_waitcnt vmcnt(2)" ::: "memory")
#define VMCNT0() asm volatile("s_waitcnt vmcnt(0)" ::: "memory")
#define LGKM0()  asm volatile("s_waitcnt lgkmcnt(0)" ::: "memory")
#define SBAR()   __builtin_amdgcn_s_barrier()
#define SCHED0() __builtin_amdgcn_sched_barrier(0)

__device__ __forceinline__ float bf2f(short s) {
    union { unsigned u; float f; } v; v.u = ((unsigned)(unsigned short)s) << 16; return v.f;
}
__device__ __forceinline__ short f2bf(float f) {
    union { float f; unsigned u; } v; v.f = f;
    unsigned r = (v.u + 0x7FFFu + ((v.u >> 16) & 1u)) >> 16;
    return (short)r;
}
__device__ __forceinline__ float phi_f(float x) {
    return x / (1.f + __expf(-x)) + 1.f;   // silu(x)+1
}
__device__ __forceinline__ void gl_lds16(const void* g, void* l) {
    __builtin_amdgcn_global_load_lds((const __attribute__((address_space(1))) void*)g,
                                     (__attribute__((address_space(3))) void*)l, 16, 0, 0);
}

// LDS chunk swizzle (measured 0 conflicts in r5): physical slot p holds global
// chunk p ^ ((row>>1)&3). Stage pre-swizzles the GLOBAL source (LDS stays
// linear for global_load_lds); reads apply the same XOR.

// ---------------- weight cast fp32 -> bf16 ----------------
__global__ __launch_bounds__(256)
void conv_w_kernel(const float* __restrict__ w0, const float* __restrict__ w1,
                   const float* __restrict__ w2, const float* __restrict__ w3,
                   short* __restrict__ o0, short* __restrict__ o1,
                   short* __restrict__ o2, short* __restrict__ o3)
{
    const int i = (blockIdx.x * 256 + threadIdx.x) * 4;
    float4v a = *(const float4v*)(w0 + i);
    float4v b = *(const float4v*)(w1 + i);
    float4v c = *(const float4v*)(w2 + i);
    float4v d = *(const float4v*)(w3 + i);
    short4v ra, rb, rc, rd;
#pragma unroll
    for (int j = 0; j < 4; ++j) {
        ra[j] = f2bf(a[j]); rb[j] = f2bf(b[j]); rc[j] = f2bf(c[j]); rd[j] = f2bf(d[j]);
    }
    *(short4v*)(o0 + i) = ra;
    *(short4v*)(o1 + i) = rb;
    *(short4v*)(o2 + i) = rc;
    *(short4v*)(o3 + i) = rd;
}

// ------- transpose-cast (B,C,T)fp32 -> (B,TP,C)bf16, zero-pad t>=TQ; x and xa merged -------
__global__ __launch_bounds__(256)
void xpose_kernel(const float* __restrict__ x, const float* __restrict__ xa,
                  short* __restrict__ xT, short* __restrict__ xaT)
{
    __shared__ float tile[64][65];
    const int z  = blockIdx.z;
    const int b  = z & 7;
    const float* src = (z < 8) ? x : xa;
    short* dst       = (z < 8) ? xT : xaT;
    const int c0 = blockIdx.y * 64;
    const int t0 = blockIdx.x * 64;
    const int tl = threadIdx.x & 63;
    const int q  = threadIdx.x >> 6;
    const int t  = t0 + tl;
#pragma unroll
    for (int i = 0; i < 16; ++i) {
        const int cl = q * 16 + i;
        float v = 0.f;
        if (t < TQ) v = src[((size_t)b * CC + c0 + cl) * TQ + t];
        tile[cl][tl] = v;
    }
    __syncthreads();
#pragma unroll
    for (int i = 0; i < 16; ++i) {
        const int t2 = q * 16 + i;
        dst[((size_t)b * TP + t0 + t2) * CC + c0 + tl] = f2bf(tile[tl][t2]);
    }
}

// =====================================================================
// Pipelined GEMM skeleton (all 3 GEMMs): 512 thr (8 waves, 4M x 2N),
// BM=128, BK=32, quad-buffered LDS (A 8KB + B 8KB per buf = 64 KB),
// stage-ahead 3 K-tiles, 1 raw s_barrier / K-tile, counted vmcnt(4)
// (never 0 in steady state), lgkmcnt(0)+sched_barrier+setprio around MFMA.
// =====================================================================

// ------- gemm_q_out : pq = phi(Wq x + bq); den-reduce; outT = pq*kvsum*0.125/(den+eps) -------
// grid 768 = 96 m-tiles x 8 n-tiles; XCD-swizzled, nt fastest
__global__ __launch_bounds__(512, 4)
void gemm_q_out_kernel(const short* __restrict__ xT, const short* __restrict__ Wqb,
                       const float* __restrict__ bq, const float* __restrict__ ksum,
                       const float* __restrict__ kvsum, short* __restrict__ outT)
{
    __shared__ short lds[4][8192];   // [buf][A 4096 | B 4096]
    const int f    = blockIdx.x;
    const int L    = (f & 7) * 96 + (f >> 3);
    const int nt   = L % 8;
    const int mrow = L / 8;          // 0..95 (128-row tile of flat 12288)
    const int b    = mrow / 12;
    const int tid  = threadIdx.x;
    const int wave = tid >> 6, lane = tid & 63;
    const int wr = wave >> 1;        // 0..3 : m 32-span
    const int wc = wave & 1;         // 0..1 : n 64-span
    const int rl = lane & 15;
    const int q4 = lane >> 4;
    const int rg = (q4 ^ ((rl >> 1) & 3)) << 3;
    const int rgrp = q4;

    const int srow = tid >> 2;
    const int skc  = ((tid & 3) ^ ((srow >> 1) & 3)) << 3;
    const short* aSrc = xT  + (size_t)(mrow * 128 + srow) * CC + skc;
    const short* bSrc = Wqb + (size_t)(nt   * 128 + srow) * CC + skc;
    const int dstOff = wave * 512;

    const int aoff0 = (wr * 32 + rl) * 32 + rg;
    const int boff0 = 4096 + (wc * 64 + rl) * 32 + rg;

    f32x4 acc[2][4] = {};

#pragma unroll
    for (int k0 = 0; k0 < 3; ++k0) {
        gl_lds16(aSrc + k0 * 32, &lds[k0][dstOff]);
        gl_lds16(bSrc + k0 * 32, &lds[k0][4096 + dstOff]);
    }
    VMCNT4(); SBAR();

#pragma unroll 1
    for (int kt = 0; kt < 32; ++kt) {
        if (kt < 29) {
            const int pn = (kt + 3) & 3;
            gl_lds16(aSrc + (kt + 3) * 32, &lds[pn][dstOff]);
            gl_lds16(bSrc + (kt + 3) * 32, &lds[pn][4096 + dstOff]);
        }
        const int p = kt & 3;
        const short* ba = &lds[p][aoff0];
        const short* bb = &lds[p][boff0];
        short8 ra[2], rb[4];
        ra[0] = *(const short8*)(ba);
        ra[1] = *(const short8*)(ba + 512);
        rb[0] = *(const short8*)(bb);
        rb[1] = *(const short8*)(bb + 512);
        rb[2] = *(const short8*)(bb + 1024);
        rb[3] = *(const short8*)(bb + 1536);
        LGKM0(); SCHED0();
        __builtin_amdgcn_s_setprio(1);
#pragma unroll
        for (int i = 0; i < 2; ++i)
#pragma unroll
            for (int j = 0; j < 4; ++j)
                acc[i][j] = __builtin_amdgcn_mfma_f32_16x16x32_bf16(ra[i], rb[j], acc[i][j], 0, 0, 0);
        __builtin_amdgcn_s_setprio(0);
        if (kt < 29)       { VMCNT4(); }
        else if (kt == 29) { VMCNT2(); }
        else if (kt == 30) { VMCNT0(); }
        if (kt < 31) SBAR();
    }

    // ---- fused epilogue: wave wc's 64-col span = one full head ----
    float bias[4], ks[4], kv[4];
#pragma unroll
    for (int j = 0; j < 4; ++j) {
        const int c = nt * 128 + wc * 64 + j * 16 + rl;
        bias[j] = bq[c];
        ks[j]   = ksum[b * CC + c];
        kv[j]   = kvsum[b * CC + c];
    }
#pragma unroll
    for (int i = 0; i < 2; ++i)
#pragma unroll
        for (int j = 0; j < 4; ++j)
#pragma unroll
            for (int r = 0; r < 4; ++r)
                acc[i][j][r] = phi_f(acc[i][j][r] + bias[j]);
#pragma unroll
    for (int i = 0; i < 2; ++i) {
#pragma unroll
        for (int r = 0; r < 4; ++r) {
            float d = acc[i][0][r] * ks[0] + acc[i][1][r] * ks[1]
                    + acc[i][2][r] * ks[2] + acc[i][3][r] * ks[3];
            d += __shfl_xor(d, 1); d += __shfl_xor(d, 2);
            d += __shfl_xor(d, 4); d += __shfl_xor(d, 8);
            const float inv = 0.125f / (d + EPS);
            const int trow = mrow * 128 + wr * 32 + i * 16 + rgrp * 4 + r;
#pragma unroll
            for (int j = 0; j < 4; ++j) {
                const int c = nt * 128 + wc * 64 + j * 16 + rl;
                outT[(size_t)trow * CC + c] = f2bf(acc[i][j][r] * kv[j] * inv);
            }
        }
    }
}

// ------- gemm_kv : dual GEMM (k,v) fused phi + t-reduction -> ksum/kvsum -------
// grid 1536 = 96 m-tiles x 16 c-tiles (64 cols each); B-LDS rows 0-63 = Wk, 64-127 = Wv
__global__ __launch_bounds__(512, 4)
void gemm_kv_kernel(const short* __restrict__ xaT, const short* __restrict__ Wkb,
                    const short* __restrict__ Wvb, const float* __restrict__ bv,
                    float* __restrict__ ksum, float* __restrict__ kvsum)
{
    __shared__ short lds[4][8192];
    const int f    = blockIdx.x;
    const int L    = (f & 7) * 192 + (f >> 3);
    const int cb   = L % 16;
    const int mrow = L / 16;         // 0..95
    const int b    = mrow / 12;
    const int tid  = threadIdx.x;
    const int wave = tid >> 6, lane = tid & 63;
    const int wr = wave >> 1;
    const int wc = wave & 1;         // 0..1 : c 32-span
    const int rl = lane & 15;
    const int q4 = lane >> 4;
    const int rg = (q4 ^ ((rl >> 1) & 3)) << 3;
    const int rgrp = q4;

    const int srow = tid >> 2;
    const int skc  = ((tid & 3) ^ ((srow >> 1) & 3)) << 3;
    const short* aSrc = xaT + (size_t)(mrow * 128 + srow) * CC + skc;
    const short* bSrc = (srow < 64)
        ? Wkb + (size_t)(cb * 64 + srow) * CC + skc
        : Wvb + (size_t)(cb * 64 + srow - 64) * CC + skc;
    const int dstOff = wave * 512;

    const int aoff0 = (wr * 32 + rl) * 32 + rg;
    const int boffK = 4096 + (wc * 32 + rl) * 32 + rg;           // + j*512, j=0,1
    const int boffV = boffK + 2048;                              // + (j-2)*512

    f32x4 acc[2][4] = {};   // [i][0..1]=k, [i][2..3]=v (same c as j-2)

#pragma unroll
    for (int k0 = 0; k0 < 3; ++k0) {
        gl_lds16(aSrc + k0 * 32, &lds[k0][dstOff]);
        gl_lds16(bSrc + k0 * 32, &lds[k0][4096 + dstOff]);
    }
    VMCNT4(); SBAR();

#pragma unroll 1
    for (int kt = 0; kt < 32; ++kt) {
        if (kt < 29) {
            const int pn = (kt + 3) & 3;
            gl_lds16(aSrc + (kt + 3) * 32, &lds[pn][dstOff]);
            gl_lds16(bSrc + (kt + 3) * 32, &lds[pn][4096 + dstOff]);
        }
        const int p = kt & 3;
        const short* ba = &lds[p][aoff0];
        short8 ra[2], rb[4];
        ra[0] = *(const short8*)(ba);
        ra[1] = *(const short8*)(ba + 512);
        rb[0] = *(const short8*)(&lds[p][boffK]);
        rb[1] = *(const short8*)(&lds[p][boffK + 512]);
        rb[2] = *(const short8*)(&lds[p][boffV]);
        rb[3] = *(const short8*)(&lds[p][boffV + 512]);
        LGKM0(); SCHED0();
        __builtin_amdgcn_s_setprio(1);
#pragma unroll
        for (int i = 0; i < 2; ++i)
#pragma unroll
            for (int j = 0; j < 4; ++j)
                acc[i][j] = __builtin_amdgcn_mfma_f32_16x16x32_bf16(ra[i], rb[j], acc[i][j], 0, 0, 0);
        __builtin_amdgcn_s_setprio(0);
        if (kt < 29)       { VMCNT4(); }
        else if (kt == 29) { VMCNT2(); }
        else if (kt == 30) { VMCNT0(); }
        if (kt < 31) SBAR();
    }

    const int tbase = (mrow % 12) * 128 + wr * 32 + rgrp * 4;
#pragma unroll
    for (int jj = 0; jj < 2; ++jj) {
        const int c = cb * 64 + wc * 32 + jj * 16 + rl;
        const float bvc = bv[c];
        float sk = 0.f, skv = 0.f;
#pragma unroll
        for (int i = 0; i < 2; ++i) {
#pragma unroll
            for (int r = 0; r < 4; ++r) {
                if (tbase + i * 16 + r < TQ) {
                    float pk = phi_f(acc[i][jj][r]);
                    float vv = acc[i][jj + 2][r] + bvc;
                    sk  += pk;
                    skv += pk * vv;
                }
            }
        }
        sk  += __shfl_xor(sk, 16);  sk  += __shfl_xor(sk, 32);
        skv += __shfl_xor(skv, 16); skv += __shfl_xor(skv, 32);
        if (rgrp == 0) {
            atomicAdd(&ksum[b * CC + c], sk);
            atomicAdd(&kvsum[b * CC + c], skv);
        }
    }
}

// ---------------- gemm_o : y[b][c][t] = Wo out + bo, m=c n=t, mask t<TQ ----------------
// grid 768 = (8 b x 12 tt) x 8 ct; XCD-swizzled, ct fastest
__global__ __launch_bounds__(512, 4)
void gemm_o_kernel(const short* __restrict__ Wob, const short* __restrict__ outT,
                   const float* __restrict__ bo, float* __restrict__ y)
{
    __shared__ short lds[4][8192];
    const int f    = blockIdx.x;
    const int L    = (f & 7) * 96 + (f >> 3);
    const int ct   = L % 8;
    const int rest = L / 8;          // 0..95 = b*12 + tt
    const int b    = rest / 12;
    const int tt   = rest % 12;
    const int tid  = threadIdx.x;
    const int wave = tid >> 6, lane = tid & 63;
    const int wr = wave >> 1;        // m = c
    const int wc = wave & 1;         // n = t 64-span
    const int rl = lane & 15;
    const int q4 = lane >> 4;
    const int rg = (q4 ^ ((rl >> 1) & 3)) << 3;
    const int rgrp = q4;

    const int srow = tid >> 2;
    const int skc  = ((tid & 3) ^ ((srow >> 1) & 3)) << 3;
    const short* aSrc = Wob  + (size_t)(ct * 128 + srow) * CC + skc;
    const short* bSrc = outT + (size_t)(rest * 128 + srow) * CC + skc;
    const int dstOff = wave * 512;

    const int aoff0 = (wr * 32 + rl) * 32 + rg;
    const int boff0 = 4096 + (wc * 64 + rl) * 32 + rg;

    f32x4 acc[2][4] = {};

#pragma unroll
    for (int k0 = 0; k0 < 3; ++k0) {
        gl_lds16(aSrc + k0 * 32, &lds[k0][dstOff]);
        gl_lds16(bSrc + k0 * 32, &lds[k0][4096 + dstOff]);
    }
    VMCNT4(); SBAR();

#pragma unroll 1
    for (int kt = 0; kt < 32; ++kt) {
        if (kt < 29) {
            const int pn = (kt + 3) & 3;
            gl_lds16(aSrc + (kt + 3) * 32, &lds[pn][dstOff]);
            gl_lds16(bSrc + (kt + 3) * 32, &lds[pn][4096 + dstOff]);
        }
        const int p = kt & 3;
        const short* ba = &lds[p][aoff0];
        const short* bb = &lds[p][boff0];
        short8 ra[2], rb[4];
        ra[0] = *(const short8*)(ba);
        ra[1] = *(const short8*)(ba + 512);
        rb[0] = *(const short8*)(bb);
        rb[1] = *(const short8*)(bb + 512);
        rb[2] = *(const short8*)(bb + 1024);
        rb[3] = *(const short8*)(bb + 1536);
        LGKM0(); SCHED0();
        __builtin_amdgcn_s_setprio(1);
#pragma unroll
        for (int i = 0; i < 2; ++i)
#pragma unroll
            for (int j = 0; j < 4; ++j)
                acc[i][j] = __builtin_amdgcn_mfma_f32_16x16x32_bf16(ra[i], rb[j], acc[i][j], 0, 0, 0);
        __builtin_amdgcn_s_setprio(0);
        if (kt < 29)       { VMCNT4(); }
        else if (kt == 29) { VMCNT2(); }
        else if (kt == 30) { VMCNT0(); }
        if (kt < 31) SBAR();
    }

#pragma unroll
    for (int j = 0; j < 4; ++j) {
        const int t = tt * 128 + wc * 64 + j * 16 + rl;
        if (t >= TQ) continue;
#pragma unroll
        for (int i = 0; i < 2; ++i) {
            const int cbase = ct * 128 + wr * 32 + i * 16 + rgrp * 4;
#pragma unroll
            for (int r = 0; r < 4; ++r) {
                const int c = cbase + r;
                y[((size_t)b * CC + c) * TQ + t] = acc[i][j][r] + bo[c];
            }
        }
    }
}

extern "C" void kernel_launch(void* const* d_in, const int* in_sizes, int n_in,
                              void* d_out, int out_size, void* d_ws, size_t ws_size,
                              hipStream_t stream)
{
    (void)in_sizes; (void)n_in; (void)out_size; (void)ws_size;
    const float* x  = (const float*)d_in[0];
    const float* xa = (const float*)d_in[1];
    const float* Wq = (const float*)d_in[2];
    const float* bq = (const float*)d_in[3];
    const float* Wk = (const float*)d_in[4];
    const float* Wv = (const float*)d_in[5];
    const float* bv = (const float*)d_in[6];
    const float* Wo = (const float*)d_in[7];
    const float* bo = (const float*)d_in[8];
    float* y = (float*)d_out;
    char* ws = (char*)d_ws;

    short* xT    = (short*)(ws + XT_OFF);
    short* xaT   = (short*)(ws + XAT_OFF);
    short* outT  = (short*)(ws + OUT_OFF);
    short* Wqb   = (short*)(ws + WB_OFF);
    short* Wkb   = Wqb + (size_t)CC * CC;
    short* Wvb   = Wkb + (size_t)CC * CC;
    short* Wob   = Wvb + (size_t)CC * CC;
    float* ksum  = (float*)(ws + KSUM_OFF);
    float* kvsum = (float*)(ws + KVSUM_OFF);

    conv_w_kernel<<<dim3(CC * CC / 4 / 256), 256, 0, stream>>>(Wq, Wk, Wv, Wo, Wqb, Wkb, Wvb, Wob);
    xpose_kernel<<<dim3(TP / 64, CC / 64, 16), 256, 0, stream>>>(x, xa, xT, xaT);
    hipMemsetAsync(ws + KSUM_OFF, 0, 65536, stream);

    gemm_kv_kernel<<<dim3(1536), 512, 0, stream>>>(xaT, Wkb, Wvb, bv, ksum, kvsum);
    gemm_q_out_kernel<<<dim3(768), 512, 0, stream>>>(xT, Wqb, bq, ksum, kvsum, outT);
    gemm_o_kernel<<<dim3(768), 512, 0, stream>>>(Wob, outT, bo, y);
}